// Round 15
// baseline (28.979 us; speedup 1.0000x reference)
//
#include <hip/hip_runtime.h>
#include <math.h>

// ---- problem constants ----
// SIZE=(60,270,480); CHANNELS=14; GRIDS: (60,16,16,8),(30,8,8,4),(15,4,4,2)
// IDX_MAX=(60,3,5) -> patch=(1,90,96); PADDING=(0,1,1) -> ppad=(1,92,98)
// t_embed: [64][1][92][98][14] = 8,078,336 f32 ; t_manip: [64][16]

#define N_PATCH 64
#define PPAD_H 92
#define PPAD_W 98
#define CH 14
#define PIX_PER_PATCH (PPAD_H * PPAD_W)        // 9016
#define ROWS_PER_BLOCK 2
#define BLOCKS_PER_PATCH 46
#define F4_PER_ROW (PPAD_W * CH / 4)           // 343
#define F4_PER_BLOCK (2 * F4_PER_ROW)          // 686
#define ELEMS_PER_PATCH (PIX_PER_PATCH * CH)   // 126224
#define ELEMS_PER_BLOCK (2 * PPAD_W * CH)      // 2744
#define TOTAL_EMBED (N_PATCH * ELEMS_PER_PATCH)
#define TOTAL_MANIP (N_PATCH * 16)

// V-record per row (floats): L0 [0,48)=6cells*8ch, L1 [48,64)=4*4, L2 [64,70)=3*2
#define RB_STRIDE 72
#define L1_OFF 48
#define L2_OFF 64
// interleaved BD table per row: 28 float4 units (B.x,B.y,D.x,D.y)
//   L0: u=0..19  (5 slots x 4 ch-units, cs=8)
//   L1: u=20..25 (3 slots x 2 ch-units, cs=4)
//   L2: u=26..27 (2 slots x 1 ch-unit,  cs=2)
#define BD_UNITS 28

#define SW0 ((float)((double)16 / 480.0))
#define SW1 ((float)((double)8  / 480.0))
#define SW2 ((float)((double)4  / 480.0))
#define SH0 ((float)((double)16 / 270.0))
#define SH1 ((float)((double)8  / 270.0))
#define SH2 ((float)((double)4  / 270.0))

__device__ __forceinline__ float lerpf(float a, float b, float f) {
    return a + f * (b - a);
}

// unclamped leftmost w-cell index (w0 of rw0)
__device__ __forceinline__ int wcell0u(int rw0, float sw) {
    float x = ((float)rw0 + 0.5f) * sw - 0.5f;
    return (int)floorf(x);
}

__global__ __launch_bounds__(256) void embed_kernel(
    const int* __restrict__ idx,
    const float* __restrict__ g0,
    const float* __restrict__ g1,
    const float* __restrict__ g2,
    float* __restrict__ out)
{
    __shared__ __align__(16) float  s_V[ROWS_PER_BLOCK][RB_STRIDE];   // 576 B
    __shared__ __align__(16) float4 s_BD[ROWS_PER_BLOCK][BD_UNITS];   // 896 B

    const int tid = threadIdx.x;
    const int bx  = blockIdx.x;
    const int n   = blockIdx.y;
    const int it  = idx[3 * n + 0];
    const int ih  = idx[3 * n + 1];
    const int iw  = idx[3 * n + 2];
    const int rw0 = iw * 96 - 1;

    const int C0u0 = wcell0u(rw0, SW0);
    const int C0u1 = wcell0u(rw0, SW1);
    const int C0u2 = wcell0u(rw0, SW2);
    const int C0_0 = min(max(C0u0, 0), 15);
    const int C0_1 = min(max(C0u1, 0), 7);
    const int C0_2 = min(max(C0u2, 0), 3);

    // ---- fused manip (one block only) ----
    if (bx == 0 && n == 0) {
        float* om = out + TOTAL_EMBED;
        for (int e = tid; e < TOTAL_MANIP; e += 256) {
            int nn = e >> 4;
            int j  = e & 15;
            int l  = j & 7;
            float base = (float)M_PI * (float)(1 << l);  // fl32(2^l*pi), pow2 exact
            float v = (float)idx[3 * nn + 0] * base;     // f32 mul = reference
            double dv = (double)v;
            om[e] = (float)((j < 8) ? sin(dv) : cos(dv));
        }
    }

    // ---- stage 1: V tables (h,t-lerped, row-mask folded), 140 entries ----
    if (tid < 96) {
        int chn  = tid & 7;
        int u    = tid >> 3;
        int row  = (u >= 6);
        int cell = u - 6 * row;
        int rh   = ih * 90 + (bx * 2 + row) - 1;
        float mh = ((unsigned)rh < 270u) ? 1.0f : 0.0f;
        float xh = ((float)rh + 0.5f) * SH0 - 0.5f;
        float ff = floorf(xh);
        float fh = xh - ff;
        int h0 = (int)ff;
        int h0c = min(max(h0, 0), 15), h1c = min(h0 + 1, 15);
        int cw = min(C0_0 + cell, 15);
        const float* base = g0 + (size_t)it * 2048;
        float a = base[(h0c * 16 + cw) * 8 + chn];
        float b = base[(h1c * 16 + cw) * 8 + chn];
        s_V[row][cell * 8 + chn] = mh * lerpf(a, b, fh);
    } else if (tid < 128) {
        int i    = tid - 96;
        int chn  = i & 3;
        int u    = i >> 2;
        int row  = (u >= 4);
        int cell = u - 4 * row;
        int rh   = ih * 90 + (bx * 2 + row) - 1;
        float mh = ((unsigned)rh < 270u) ? 1.0f : 0.0f;
        float xh = ((float)rh + 0.5f) * SH1 - 0.5f;
        float ff = floorf(xh);
        float fh = xh - ff;
        int h0 = (int)ff;
        int h0c = min(max(h0, 0), 7), h1c = min(h0 + 1, 7);
        float xt = ((float)it + 0.5f) * 0.5f - 0.5f;     // 30/60 exact
        float ftf = floorf(xt);
        float ft  = xt - ftf;
        int t0 = (int)ftf;
        int t0c = min(max(t0, 0), 29), t1c = min(t0 + 1, 29);
        int cw = min(C0_1 + cell, 7);
        float a00 = g1[((t0c * 8 + h0c) * 8 + cw) * 4 + chn];
        float a01 = g1[((t0c * 8 + h1c) * 8 + cw) * 4 + chn];
        float a10 = g1[((t1c * 8 + h0c) * 8 + cw) * 4 + chn];
        float a11 = g1[((t1c * 8 + h1c) * 8 + cw) * 4 + chn];
        s_V[row][L1_OFF + cell * 4 + chn] =
            mh * lerpf(lerpf(a00, a01, fh), lerpf(a10, a11, fh), ft);
    } else if (tid < 140) {
        int i    = tid - 128;
        int chn  = i & 1;
        int u    = i >> 1;
        int row  = (u >= 3);
        int cell = u - 3 * row;
        int rh   = ih * 90 + (bx * 2 + row) - 1;
        float mh = ((unsigned)rh < 270u) ? 1.0f : 0.0f;
        float xh = ((float)rh + 0.5f) * SH2 - 0.5f;
        float ff = floorf(xh);
        float fh = xh - ff;
        int h0 = (int)ff;
        int h0c = min(max(h0, 0), 3), h1c = min(h0 + 1, 3);
        float xt = ((float)it + 0.5f) * 0.25f - 0.5f;    // 15/60 exact
        float ftf = floorf(xt);
        float ft  = xt - ftf;
        int t0 = (int)ftf;
        int t0c = min(max(t0, 0), 14), t1c = min(t0 + 1, 14);
        int cw = min(C0_2 + cell, 3);
        float a00 = g2[((t0c * 4 + h0c) * 4 + cw) * 2 + chn];
        float a01 = g2[((t0c * 4 + h1c) * 4 + cw) * 2 + chn];
        float a10 = g2[((t1c * 4 + h0c) * 4 + cw) * 2 + chn];
        float a11 = g2[((t1c * 4 + h1c) * 4 + cw) * 2 + chn];
        s_V[row][L2_OFF + cell * 2 + chn] =
            mh * lerpf(lerpf(a00, a01, fh), lerpf(a10, a11, fh), ft);
    }
    __syncthreads();

    // ---- stage 1.5: interleaved BD table (clamping baked in), 224 entries ----
    // entry float: row = k/112, u = (k%112)/4, c = k%4  ->  s_BD[row][u][c]
    if (tid < 224) {
        int row = tid >= 112;
        int o   = tid - 112 * row;
        int u   = o >> 2;
        int c   = o & 3;
        int s0, cs, vb, C0u, C0c, Wg1, ch;
        if (u < 20)      { s0 = u >> 2;        cs = 8; vb = 0;      C0u = C0u0; C0c = C0_0; Wg1 = 15; ch = 2 * (u & 3); }
        else if (u < 26) { int uu = u - 20; s0 = uu >> 1; cs = 4; vb = L1_OFF; C0u = C0u1; C0c = C0_1; Wg1 = 7;  ch = 2 * (uu & 1); }
        else             { s0 = u - 26;        cs = 2; vb = L2_OFF; C0u = C0u2; C0c = C0_2; Wg1 = 3;  ch = 0; }
        int w0 = C0u + s0;
        int wa = min(max(w0, 0), Wg1);
        int wb = min(w0 + 1, Wg1);
        int cc = c & 1;
        float va  = s_V[row][vb + (wa - C0c) * cs + ch + cc];
        float vbv = s_V[row][vb + (wb - C0c) * cs + ch + cc];
        ((float*)&s_BD[row][u])[c] = (c < 2) ? va : (vbv - va);  // DIF = V[wb]-V[wa]
    }
    __syncthreads();

    // ---- stage 2: one thread per output float4; direct coalesced stores ----
    float4* gb = (float4*)(out + (size_t)n * ELEMS_PER_PATCH + bx * ELEMS_PER_BLOCK);

    auto pairval = [&](int P, int row, float& rx, float& ry) {
        int p = P / 7;                     // pair -> pixel, channel-pair q
        int q = P - 7 * p;
        int rw = iw * 96 + p - 1;
        float mw = ((unsigned)rw < 480u) ? 1.0f : 0.0f;
        float rwc = (float)rw + 0.5f;
        int lvl = (q >= 4) + (q >= 6);
        float sw  = (lvl == 0) ? SW0 : ((lvl == 1) ? SW1 : SW2);
        int   C0u = (lvl == 0) ? C0u0 : ((lvl == 1) ? C0u1 : C0u2);
        float x  = rwc * sw - 0.5f;
        float ffl = floorf(x);
        float fw = x - ffl;
        int s0 = (int)ffl - C0u;
        int unit = (lvl == 0) ? (s0 * 4 + q)
                 : ((lvl == 1) ? (20 + s0 * 2 + (q - 4)) : (26 + s0));
        float4 bd = s_BD[row][unit];
        rx = mw * fmaf(fw, bd.z, bd.x);
        ry = mw * fmaf(fw, bd.w, bd.y);
    };

    auto do_f4 = [&](int j) {
        int row = j >= F4_PER_ROW;
        int P0  = 2 * (j - F4_PER_ROW * row);
        float r0x, r0y, r1x, r1y;
        pairval(P0,     row, r0x, r0y);
        pairval(P0 + 1, row, r1x, r1y);
        gb[j] = make_float4(r0x, r0y, r1x, r1y);
    };

    do_f4(tid);
    do_f4(tid + 256);
    if (tid < F4_PER_BLOCK - 512) do_f4(tid + 512);
}

extern "C" void kernel_launch(void* const* d_in, const int* in_sizes, int n_in,
                              void* d_out, int out_size, void* d_ws, size_t ws_size,
                              hipStream_t stream) {
    const int*   idx = (const int*)  d_in[0];
    const float* g0  = (const float*)d_in[3];
    const float* g1  = (const float*)d_in[4];
    const float* g2  = (const float*)d_in[5];
    float* out = (float*)d_out;

    dim3 grid(BLOCKS_PER_PATCH, N_PATCH);   // (46, 64) = 2944 blocks
    embed_kernel<<<grid, 256, 0, stream>>>(idx, g0, g1, g2, out);
}

// Round 16
// 13.455 us; speedup vs baseline: 2.1538x; 2.1538x over previous
//
#include <hip/hip_runtime.h>
#include <math.h>

// ---- problem constants ----
// SIZE=(60,270,480); CHANNELS=14; GRIDS: (60,16,16,8),(30,8,8,4),(15,4,4,2)
// IDX_MAX=(60,3,5) -> patch=(1,90,96); PADDING=(0,1,1) -> ppad=(1,92,98)
// t_embed: [64][1][92][98][14] = 8,078,336 f32 ; t_manip: [64][16]

#define N_PATCH 64
#define HALF_N 32
#define PPAD_H 92
#define PPAD_W 98
#define CH 14
#define PIX_PER_PATCH (PPAD_H * PPAD_W)        // 9016
#define BLOCKS_PER_PATCH 46                    // 2 rows per block
#define PX_PER_BLOCK 196
#define F4_PER_BLOCK (PX_PER_BLOCK * CH / 4)   // 686
#define ELEMS_PER_PATCH (PIX_PER_PATCH * CH)   // 126224
#define ELEMS_PER_BLOCK (PX_PER_BLOCK * CH)    // 2744
#define TOTAL_EMBED (N_PATCH * ELEMS_PER_PATCH)
#define TOTAL_MANIP (N_PATCH * 16)

// V-record per row (floats): L0 [0,48)=6cells*8ch, L1 [48,64)=4*4, L2 [64,70)=3*2
#define RB_STRIDE 72
#define L1_OFF 48
#define L2_OFF 64

#define SW0 ((float)((double)16 / 480.0))
#define SW1 ((float)((double)8  / 480.0))
#define SW2 ((float)((double)4  / 480.0))
#define SH0 ((float)((double)16 / 270.0))
#define SH1 ((float)((double)8  / 270.0))
#define SH2 ((float)((double)4  / 270.0))

__device__ __forceinline__ float lerpf(float a, float b, float f) {
    return a + f * (b - a);
}

__device__ __forceinline__ int wcell0(int rw0, float sw, int Wg) {
    float x = ((float)rw0 + 0.5f) * sw - 0.5f;
    int w0 = (int)floorf(x);
    return min(max(w0, 0), Wg - 1);
}

// LDS-only barrier: does NOT drain vmcnt (global stores stay in flight).
__device__ __forceinline__ void lds_barrier() {
    asm volatile("s_waitcnt lgkmcnt(0)" ::: "memory");
    __builtin_amdgcn_sched_barrier(0);
    __builtin_amdgcn_s_barrier();
    __builtin_amdgcn_sched_barrier(0);
}

// ---- issue this thread's V-input gathers for one tile (kept in registers) ----
__device__ __forceinline__ float4 load_vin(int tid, int bx, int it, int ih,
                                           int C0_0, int C0_1, int C0_2,
                                           const float* __restrict__ g0,
                                           const float* __restrict__ g1,
                                           const float* __restrict__ g2)
{
    float4 r = make_float4(0.f, 0.f, 0.f, 0.f);
    if (tid < 96) {
        int chn = tid & 7, u = tid >> 3;
        int row = (u >= 6), cell = u - 6 * row;
        int rh = ih * 90 + (bx * 2 + row) - 1;
        float xh = ((float)rh + 0.5f) * SH0 - 0.5f;
        int h0 = (int)floorf(xh);
        int h0c = min(max(h0, 0), 15), h1c = min(h0 + 1, 15);
        int cw = min(C0_0 + cell, 15);
        const float* base = g0 + (size_t)it * 2048;
        r.x = base[(h0c * 16 + cw) * 8 + chn];
        r.y = base[(h1c * 16 + cw) * 8 + chn];
    } else if (tid < 128) {
        int i = tid - 96;
        int chn = i & 3, u = i >> 2;
        int row = (u >= 4), cell = u - 4 * row;
        int rh = ih * 90 + (bx * 2 + row) - 1;
        float xh = ((float)rh + 0.5f) * SH1 - 0.5f;
        int h0 = (int)floorf(xh);
        int h0c = min(max(h0, 0), 7), h1c = min(h0 + 1, 7);
        float xt = ((float)it + 0.5f) * 0.5f - 0.5f;     // 30/60 exact
        int t0 = (int)floorf(xt);
        int t0c = min(max(t0, 0), 29), t1c = min(t0 + 1, 29);
        int cw = min(C0_1 + cell, 7);
        r.x = g1[((t0c * 8 + h0c) * 8 + cw) * 4 + chn];
        r.y = g1[((t0c * 8 + h1c) * 8 + cw) * 4 + chn];
        r.z = g1[((t1c * 8 + h0c) * 8 + cw) * 4 + chn];
        r.w = g1[((t1c * 8 + h1c) * 8 + cw) * 4 + chn];
    } else if (tid < 140) {
        int i = tid - 128;
        int chn = i & 1, u = i >> 1;
        int row = (u >= 3), cell = u - 3 * row;
        int rh = ih * 90 + (bx * 2 + row) - 1;
        float xh = ((float)rh + 0.5f) * SH2 - 0.5f;
        int h0 = (int)floorf(xh);
        int h0c = min(max(h0, 0), 3), h1c = min(h0 + 1, 3);
        float xt = ((float)it + 0.5f) * 0.25f - 0.5f;    // 15/60 exact
        int t0 = (int)floorf(xt);
        int t0c = min(max(t0, 0), 14), t1c = min(t0 + 1, 14);
        int cw = min(C0_2 + cell, 3);
        r.x = g2[((t0c * 4 + h0c) * 4 + cw) * 2 + chn];
        r.y = g2[((t0c * 4 + h1c) * 4 + cw) * 2 + chn];
        r.z = g2[((t1c * 4 + h0c) * 4 + cw) * 2 + chn];
        r.w = g2[((t1c * 4 + h1c) * 4 + cw) * 2 + chn];
    }
    return r;
}

// ---- combine register inputs into the V table (identical math to R10) ----
__device__ __forceinline__ void combine_v(int tid, int bx, int it, int ih,
                                          float4 r, float (*sV)[RB_STRIDE])
{
    if (tid < 96) {
        int chn = tid & 7, u = tid >> 3;
        int row = (u >= 6), cell = u - 6 * row;
        int rh = ih * 90 + (bx * 2 + row) - 1;
        float mh = ((unsigned)rh < 270u) ? 1.0f : 0.0f;
        float xh = ((float)rh + 0.5f) * SH0 - 0.5f;
        float fh = xh - floorf(xh);
        sV[row][cell * 8 + chn] = mh * lerpf(r.x, r.y, fh);
    } else if (tid < 128) {
        int i = tid - 96;
        int chn = i & 3, u = i >> 2;
        int row = (u >= 4), cell = u - 4 * row;
        int rh = ih * 90 + (bx * 2 + row) - 1;
        float mh = ((unsigned)rh < 270u) ? 1.0f : 0.0f;
        float xh = ((float)rh + 0.5f) * SH1 - 0.5f;
        float fh = xh - floorf(xh);
        float xt = ((float)it + 0.5f) * 0.5f - 0.5f;
        float ft = xt - floorf(xt);
        sV[row][L1_OFF + cell * 4 + chn] =
            mh * lerpf(lerpf(r.x, r.y, fh), lerpf(r.z, r.w, fh), ft);
    } else if (tid < 140) {
        int i = tid - 128;
        int chn = i & 1, u = i >> 1;
        int row = (u >= 3), cell = u - 3 * row;
        int rh = ih * 90 + (bx * 2 + row) - 1;
        float mh = ((unsigned)rh < 270u) ? 1.0f : 0.0f;
        float xh = ((float)rh + 0.5f) * SH2 - 0.5f;
        float fh = xh - floorf(xh);
        float xt = ((float)it + 0.5f) * 0.25f - 0.5f;
        float ft = xt - floorf(xt);
        sV[row][L2_OFF + cell * 2 + chn] =
            mh * lerpf(lerpf(r.x, r.y, fh), lerpf(r.z, r.w, fh), ft);
    }
}

__global__ __launch_bounds__(256) void embed_kernel(
    const int* __restrict__ idx,
    const float* __restrict__ g0,
    const float* __restrict__ g1,
    const float* __restrict__ g2,
    float* __restrict__ out)
{
    __shared__ __align__(16) float s_V0[2][RB_STRIDE];        // 576 B
    __shared__ __align__(16) float s_V1[2][RB_STRIDE];        // 576 B
    __shared__ __align__(16) float s_buf[PX_PER_BLOCK * CH];  // 11 KB (shared by both tiles)

    const int tid = threadIdx.x;
    const int bx  = blockIdx.x;
    const int n0  = blockIdx.y;
    const int n1  = blockIdx.y + HALF_N;

    const int it0 = idx[3 * n0 + 0], ih0 = idx[3 * n0 + 1], iw0 = idx[3 * n0 + 2];
    const int it1 = idx[3 * n1 + 0], ih1 = idx[3 * n1 + 1], iw1 = idx[3 * n1 + 2];
    const int rw0a = iw0 * 96 - 1, rw0b = iw1 * 96 - 1;
    const int C00a = wcell0(rw0a, SW0, 16), C01a = wcell0(rw0a, SW1, 8), C02a = wcell0(rw0a, SW2, 4);
    const int C00b = wcell0(rw0b, SW0, 16), C01b = wcell0(rw0b, SW1, 8), C02b = wcell0(rw0b, SW2, 4);

    // ---- fused manip (one block only) ----
    if (bx == 0 && blockIdx.y == 0) {
        float* om = out + TOTAL_EMBED;
        for (int e = tid; e < TOTAL_MANIP; e += 256) {
            int nn = e >> 4;
            int j  = e & 15;
            int l  = j & 7;
            float base = (float)M_PI * (float)(1 << l);  // fl32(2^l*pi), pow2 exact
            float v = (float)idx[3 * nn + 0] * base;     // f32 mul = reference
            double dv = (double)v;
            om[e] = (float)((j < 8) ? sin(dv) : cos(dv));
        }
    }

    // ---- P0: issue BOTH tiles' gathers up-front (registers) ----
    float4 r0 = load_vin(tid, bx, it0, ih0, C00a, C01a, C02a, g0, g1, g2);
    float4 r1 = load_vin(tid, bx, it1, ih1, C00b, C01b, C02b, g0, g1, g2);

    // ---- per-pixel compute (identical to R10 stage 2) ----
    auto compute_tile = [&](int iwq, int C00q, int C01q, int C02q,
                            const float (*sV)[RB_STRIDE]) {
        if (tid >= PX_PER_BLOCK) return;
        int row = (tid >= PPAD_W);
        int ww  = tid - PPAD_W * row;
        int rw  = iwq * 96 + ww - 1;
        float mw = ((unsigned)rw < 480u) ? 1.0f : 0.0f;
        float rwc = (float)rw + 0.5f;

        float x0 = rwc * SW0 - 0.5f;
        float f0f = floorf(x0);
        float fw0 = x0 - f0f;
        int w00 = (int)f0f;
        int oA0 = (min(max(w00, 0), 15) - C00q) * 8;
        int oB0 = (min(w00 + 1, 15)    - C00q) * 8;
        float x1 = rwc * SW1 - 0.5f;
        float f1f = floorf(x1);
        float fw1 = x1 - f1f;
        int w01 = (int)f1f;
        int oA1 = L1_OFF + (min(max(w01, 0), 7) - C01q) * 4;
        int oB1 = L1_OFF + (min(w01 + 1, 7)     - C01q) * 4;
        float x2 = rwc * SW2 - 0.5f;
        float f2f = floorf(x2);
        float fw2 = x2 - f2f;
        int w02 = (int)f2f;
        int oA2 = L2_OFF + (min(max(w02, 0), 3) - C02q) * 2;
        int oB2 = L2_OFF + (min(w02 + 1, 3)     - C02q) * 2;

        const float* V = sV[row];
        float4 A0  = *(const float4*)(V + oA0);
        float4 A1  = *(const float4*)(V + oA0 + 4);
        float4 B0  = *(const float4*)(V + oB0);
        float4 B1  = *(const float4*)(V + oB0 + 4);
        float4 C1a = *(const float4*)(V + oA1);
        float4 C1b = *(const float4*)(V + oB1);
        float2 C2a = *(const float2*)(V + oA2);
        float2 C2b = *(const float2*)(V + oB2);

        float2* b = (float2*)(s_buf + tid * CH);
        b[0] = make_float2(mw * lerpf(A0.x, B0.x, fw0),
                           mw * lerpf(A0.y, B0.y, fw0));
        b[1] = make_float2(mw * lerpf(A0.z, B0.z, fw0),
                           mw * lerpf(A0.w, B0.w, fw0));
        b[2] = make_float2(mw * lerpf(A1.x, B1.x, fw0),
                           mw * lerpf(A1.y, B1.y, fw0));
        b[3] = make_float2(mw * lerpf(A1.z, B1.z, fw0),
                           mw * lerpf(A1.w, B1.w, fw0));
        b[4] = make_float2(mw * lerpf(C1a.x, C1b.x, fw1),
                           mw * lerpf(C1a.y, C1b.y, fw1));
        b[5] = make_float2(mw * lerpf(C1a.z, C1b.z, fw1),
                           mw * lerpf(C1a.w, C1b.w, fw1));
        b[6] = make_float2(mw * lerpf(C2a.x, C2b.x, fw2),
                           mw * lerpf(C2a.y, C2b.y, fw2));
    };

    auto store_tile = [&](int nq) {
        const float4* sb = (const float4*)s_buf;
        float4* gb = (float4*)(out + (size_t)nq * ELEMS_PER_PATCH + bx * ELEMS_PER_BLOCK);
        for (int j = tid; j < F4_PER_BLOCK; j += 256) gb[j] = sb[j];
    };

    // ---- pipeline: tile0 then tile1; stores never drained by a barrier ----
    combine_v(tid, bx, it0, ih0, r0, s_V0);   // waits only r0's loads (counted vmcnt)
    lds_barrier();

    compute_tile(iw0, C00a, C01a, C02a, s_V0);
    lds_barrier();

    store_tile(n0);                            // global stores fly; no vmcnt drain
    combine_v(tid, bx, it1, ih1, r1, s_V1);    // overlaps with store0
    lds_barrier();                             // retires store0's ds_reads + V1 writes

    compute_tile(iw1, C00b, C01b, C02b, s_V1); // safe: s_buf reads done at barrier
    lds_barrier();

    store_tile(n1);
}

extern "C" void kernel_launch(void* const* d_in, const int* in_sizes, int n_in,
                              void* d_out, int out_size, void* d_ws, size_t ws_size,
                              hipStream_t stream) {
    const int*   idx = (const int*)  d_in[0];
    const float* g0  = (const float*)d_in[3];
    const float* g1  = (const float*)d_in[4];
    const float* g2  = (const float*)d_in[5];
    float* out = (float*)d_out;

    dim3 grid(BLOCKS_PER_PATCH, HALF_N);   // (46, 32) = 1472 blocks ~ all co-resident
    embed_kernel<<<grid, 256, 0, stream>>>(idx, g0, g1, g2, out);
}